// Round 1
// baseline (370.432 us; speedup 1.0000x reference)
//
#include <hip/hip_runtime.h>
#include <math.h>

#define KK 14          // OUT*SR sample coords per axis
#define CHK 4          // channels staged per chunk
#define TILE_F 2048    // floats per channel tile (worst-case region ~1650)
#define LUT_CAP 512    // float4 units per channel (worst-case ~413)

__global__ __launch_bounds__(256) void pooler_kernel(
    const float* __restrict__ f0, const float* __restrict__ f1,
    const float* __restrict__ f2, const float* __restrict__ f3,
    const float* __restrict__ boxes, const int* __restrict__ bidx,
    float* __restrict__ out, int N)
{
  __shared__ __align__(16) float tile[CHK][TILE_F];
  __shared__ int   lut[LUT_CAP];
  __shared__ float s_lx[KK], s_hx[KK], s_ly[KK], s_hy[KK], s_vx[KK], s_vy[KK];
  __shared__ int   s_c0[KK], s_c1[KK], s_rt[KK], s_rb[KK];

  const int n = blockIdx.x;
  if (n >= N) return;
  const int tid = threadIdx.x;

  // ---- per-box meta (wave-uniform, recomputed by every thread) ----
  const float bx1 = boxes[4*n+0], by1 = boxes[4*n+1];
  const float bx2 = boxes[4*n+2], by2 = boxes[4*n+3];
  const float area = (bx2 - bx1 + 1.0f) * (by2 - by1 + 1.0f);
  const float s    = sqrtf(area);
  int lvl = (int)floorf(4.0f + log2f(s / 224.0f + 1e-6f));
  lvl = lvl < 2 ? 2 : (lvl > 5 ? 5 : lvl);
  const int li = lvl - 2;

  int H, W; const float* feat; float scale;
  switch (li) {
    case 0:  feat = f0; H = 200; W = 304; scale = 0.25f;    break;
    case 1:  feat = f1; H = 100; W = 152; scale = 0.125f;   break;
    case 2:  feat = f2; H = 50;  W = 76;  scale = 0.0625f;  break;
    default: feat = f3; H = 25;  W = 38;  scale = 0.03125f; break;
  }
  const int b = bidx[n];
  const float x1s = bx1 * scale, y1s = by1 * scale;
  const float roiw = fmaxf(bx2 * scale - x1s, 1.0f);
  const float roih = fmaxf(by2 * scale - y1s, 1.0f);
  const float binw = roiw / 7.0f, binh = roih / 7.0f;
  const float Hm1f = (float)(H - 1), Wm1f = (float)(W - 1);
  const int   Hm1  = H - 1,          Wm1  = W - 1;

  // region bounds from first (g=0.25) and last (g=6.75) samples (monotone)
  const float yA = fminf(fmaxf(y1s + binh * 0.25f, 0.0f), Hm1f);
  const float yB = fminf(fmaxf(y1s + binh * 6.75f, 0.0f), Hm1f);
  const float xA = fminf(fmaxf(x1s + binw * 0.25f, 0.0f), Wm1f);
  const float xB = fminf(fmaxf(x1s + binw * 6.75f, 0.0f), Wm1f);
  const int y_lo  = (int)yA;
  const int y_hi  = min((int)yB + 1, Hm1);
  const int regH  = y_hi - y_lo + 1;
  const int x_lo4 = ((int)xA) & ~3;               // float4-align region start
  const int x_hi  = min((int)xB + 1, Wm1);
  const int row4  = (x_hi - x_lo4 + 4) >> 2;      // float4s per row
  const int regW4 = row4 << 2;                    // LDS row stride (floats)
  int cnt4 = regH * row4;                         // total float4s per channel
  if (cnt4 > LUT_CAP) cnt4 = LUT_CAP;             // safety (analysis: <=413)

  // ---- per-box sample tables (x: threads 0..13, y: threads 14..27) ----
  if (tid < KK) {
    const float g  = (float)(tid >> 1) + 0.25f + 0.5f * (float)(tid & 1);
    const float Xf = x1s + binw * g;
    s_vx[tid] = (Xf >= -1.0f && Xf <= (float)W) ? 1.0f : 0.0f;
    const float x = fminf(fmaxf(Xf, 0.0f), Wm1f);
    const int  x0 = (int)x;
    const float lx = x - (float)x0;
    s_lx[tid] = lx;
    s_hx[tid] = 1.0f - lx;
    s_c0[tid] = x0 - x_lo4;
    s_c1[tid] = min(x0 + 1, Wm1) - x_lo4;
  } else if (tid < 2 * KK) {
    const int i    = tid - KK;
    const float g  = (float)(i >> 1) + 0.25f + 0.5f * (float)(i & 1);
    const float Yf = y1s + binh * g;
    s_vy[i] = (Yf >= -1.0f && Yf <= (float)H) ? 1.0f : 0.0f;
    const float y = fminf(fmaxf(Yf, 0.0f), Hm1f);
    const int  y0 = (int)y;
    const float ly = y - (float)y0;
    s_ly[i] = ly;
    s_hy[i] = 1.0f - ly;
    s_rt[i] = y0 - y_lo;
    s_rb[i] = min(y0 + 1, Hm1) - y_lo;
  }
  // ---- flat float4-unit -> (row,xb) LUT, built once per block ----
  for (int u = tid; u < cnt4; u += 256) {
    const int r  = u / row4;
    const int c  = u - r * row4;
    const int xb = x_lo4 + (c << 2);
    int pk = (r << 16) | xb;                       // r<=~120, xb<=303
    if (xb + 3 > Wm1) pk |= (int)0x80000000;       // row-tail needs clamping
    lut[u] = pk;
  }
  __syncthreads();

  // ---- channel-chunk loop: stage ROI region -> LDS, then bilinear ----
  const size_t planeHW = (size_t)H * W;
  const int    cbase   = blockIdx.y << 6;          // 64 channels per block
  const bool   w4      = ((W & 3) == 0);           // levels 0-2: 16B-safe
  const int    wave    = tid >> 6, lane = tid & 63;
  const float* plane0  = feat + ((size_t)(b * 256 + cbase + wave)) * planeHW
                              + (size_t)y_lo * W;
  const size_t outb0   = ((size_t)n * 256 + cbase) * 49;

  for (int cc = 0; cc < 16; ++cc) {
    // each wave stages one channel of the 4-channel chunk
    const float* plane = plane0 + (size_t)(cc * CHK) * planeHW;
    for (int u = lane; u < cnt4; u += 64) {
      const int pk = lut[u];
      const int r  = (pk >> 16) & 0x7fff;
      const int xb = pk & 0xffff;
      const float* p = plane + r * W + xb;
      float4 v;
      if (pk >= 0) {
        if (w4) {
          v = *(const float4*)p;                   // 16B-aligned (W%4==0)
        } else {                                   // level 3 (W=38): 8B-aligned
          const float2 a = *(const float2*)p;
          const float2 c2 = *(const float2*)(p + 2);
          v = make_float4(a.x, a.y, c2.x, c2.y);
        }
      } else {                                     // row tail: clamp within row
        const int base = r * W;
        v.x = plane[base + xb];
        v.y = plane[base + min(xb + 1, Wm1)];
        v.z = plane[base + min(xb + 2, Wm1)];
        v.w = plane[base + min(xb + 3, Wm1)];
      }
      *(float4*)&tile[wave][u << 2] = v;
    }
    __syncthreads();

    if (tid < CHK * 49) {                          // tid == ch*49 + bin
      const int ch  = tid / 49;
      const int bin = tid - ch * 49;
      const int ph  = bin / 7, pw = bin - ph * 7;
      const float* T = tile[ch];
      float acc = 0.0f;
#pragma unroll
      for (int sy = 0; sy < 2; ++sy) {
        const int i  = (ph << 1) + sy;
        const int rt = s_rt[i] * regW4, rb = s_rb[i] * regW4;
        const float ly = s_ly[i], hy = s_hy[i], vy = s_vy[i];
#pragma unroll
        for (int sx = 0; sx < 2; ++sx) {
          const int j = (pw << 1) + sx;
          const int c0 = s_c0[j], c1 = s_c1[j];
          const float w00 = T[rt + c0], w01 = T[rt + c1];
          const float w10 = T[rb + c0], w11 = T[rb + c1];
          const float hx = s_hx[j], lx = s_lx[j];
          const float bil = hy * (hx * w00 + lx * w01)
                          + ly * (hx * w10 + lx * w11);
          acc += (vy * s_vx[j]) * bil;
        }
      }
      out[outb0 + (size_t)(cc * CHK) * 49 + tid] = acc * 0.25f;
    }
    __syncthreads();
  }
}

extern "C" void kernel_launch(void* const* d_in, const int* in_sizes, int n_in,
                              void* d_out, int out_size, void* d_ws, size_t ws_size,
                              hipStream_t stream) {
  const float* f0    = (const float*)d_in[0];
  const float* f1    = (const float*)d_in[1];
  const float* f2    = (const float*)d_in[2];
  const float* f3    = (const float*)d_in[3];
  const float* boxes = (const float*)d_in[4];
  const int*   bidx  = (const int*)d_in[5];
  const int N = in_sizes[5];                       // 1024 boxes
  dim3 grid(N, 4);                                 // 4 channel-splits per box
  pooler_kernel<<<grid, 256, 0, stream>>>(f0, f1, f2, f3, boxes, bidx,
                                          (float*)d_out, N);
}

// Round 2
// 280.577 us; speedup vs baseline: 1.3203x; 1.3203x over previous
//
#include <hip/hip_runtime.h>
#include <math.h>

#define TILE_F 1792    // floats per wave tile; worst-case region ~1770 (level-2, 125x6 ROI)
#define MAXI 7         // max float4 staging iterations: ceil((TILE_F/4)/64)

typedef __attribute__((address_space(3))) void lds_void;
typedef const __attribute__((address_space(1))) void g_void;

__device__ __forceinline__ void dma16(const float* g, float* l) {
  __builtin_amdgcn_global_load_lds((g_void*)g, (lds_void*)l, 16, 0, 0);
}
__device__ __forceinline__ void dma4(const float* g, float* l) {
  __builtin_amdgcn_global_load_lds((g_void*)g, (lds_void*)l, 4, 0, 0);
}

__global__ __launch_bounds__(128) void pooler_kernel(
    const float* __restrict__ f0, const float* __restrict__ f1,
    const float* __restrict__ f2, const float* __restrict__ f3,
    const float* __restrict__ boxes, const int* __restrict__ bidx,
    float* __restrict__ out, int N)
{
  __shared__ __align__(16) float tile[2][TILE_F];  // one tile per wave
  const int tid  = threadIdx.x;
  const int wave = tid >> 6, lane = tid & 63;
  const int n    = blockIdx.y;
  if (n >= N) return;

  // ---- per-box meta (wave-uniform, recomputed by every lane) ----
  const float bx1 = boxes[4*n+0], by1 = boxes[4*n+1];
  const float bx2 = boxes[4*n+2], by2 = boxes[4*n+3];
  const float area = (bx2 - bx1 + 1.0f) * (by2 - by1 + 1.0f);
  const float s    = sqrtf(area);
  int lvl = (int)floorf(4.0f + log2f(s / 224.0f + 1e-6f));
  lvl = lvl < 2 ? 2 : (lvl > 5 ? 5 : lvl);
  const int li = lvl - 2;

  int H, W; const float* feat; float scale;
  switch (li) {
    case 0:  feat = f0; H = 200; W = 304; scale = 0.25f;    break;
    case 1:  feat = f1; H = 100; W = 152; scale = 0.125f;   break;
    case 2:  feat = f2; H = 50;  W = 76;  scale = 0.0625f;  break;
    default: feat = f3; H = 25;  W = 38;  scale = 0.03125f; break;
  }
  const int b = bidx[n];
  const float x1s = bx1 * scale, y1s = by1 * scale;
  const float roiw = fmaxf(bx2 * scale - x1s, 1.0f);
  const float roih = fmaxf(by2 * scale - y1s, 1.0f);
  const float binw = roiw / 7.0f, binh = roih / 7.0f;
  const float Hm1f = (float)(H - 1), Wm1f = (float)(W - 1);
  const int   Hm1  = H - 1,          Wm1  = W - 1;

  // ---- staged region bounds (samples are monotone: first g=0.25, last g=6.75) ----
  const float yA = fminf(fmaxf(y1s + binh * 0.25f, 0.0f), Hm1f);
  const float yB = fminf(fmaxf(y1s + binh * 6.75f, 0.0f), Hm1f);
  const float xA = fminf(fmaxf(x1s + binw * 0.25f, 0.0f), Wm1f);
  const float xB = fminf(fmaxf(x1s + binw * 6.75f, 0.0f), Wm1f);
  const int y_lo  = (int)yA;
  const int y_hi  = min((int)yB + 1, Hm1);
  const int regH  = y_hi - y_lo + 1;
  const int x_lo4 = ((int)xA) & ~3;            // float4-aligned region start
  const int x_hi  = min((int)xB + 1, Wm1);
  const int row4  = ((x_hi - x_lo4 + 4) >> 2); // float4 units per row (>=1)
  const int regW4 = row4 << 2;                 // LDS row stride in floats

  // ---- per-lane bin parameters (channel-invariant; lanes 49..63 compute junk) ----
  const int bin = (lane < 49) ? lane : 0;
  const int ph = bin / 7, pw = bin - (bin / 7) * 7;
  int   rT[2], rB[2], Cc0[2], Cc1[2];
  float HY[2], LY[2], VY[2], HX[2], LX[2], VX[2];
#pragma unroll
  for (int t = 0; t < 2; ++t) {
    {   // y sample index i = 2*ph + t  →  g = ph + 0.25 + 0.5*t
      const float g  = (float)ph + 0.25f + 0.5f * (float)t;
      const float Yf = y1s + binh * g;
      VY[t] = (Yf >= -1.0f && Yf <= (float)H) ? 1.0f : 0.0f;
      const float y = fminf(fmaxf(Yf, 0.0f), Hm1f);
      const int  y0 = (int)y;
      LY[t] = y - (float)y0;  HY[t] = 1.0f - LY[t];
      rT[t] = (y0 - y_lo) * regW4;
      rB[t] = (min(y0 + 1, Hm1) - y_lo) * regW4;
    }
    {   // x sample index j = 2*pw + t
      const float g  = (float)pw + 0.25f + 0.5f * (float)t;
      const float Xf = x1s + binw * g;
      VX[t] = (Xf >= -1.0f && Xf <= (float)W) ? 1.0f : 0.0f;
      const float x = fminf(fmaxf(Xf, 0.0f), Wm1f);
      const int  x0 = (int)x;
      LX[t] = x - (float)x0;  HX[t] = 1.0f - LX[t];
      Cc0[t] = x0 - x_lo4;
      Cc1[t] = min(x0 + 1, Wm1) - x_lo4;
    }
  }

  // ---- pointers ----
  const size_t planeHW = (size_t)H * W;
  const int    cbase   = (blockIdx.x << 5) + (wave << 4);   // 16 channels per wave
  const float* plane0  = feat + ((size_t)(b * 256 + cbase)) * planeHW
                              + (size_t)y_lo * W;
  float*       outp    = out + ((size_t)n * 256 + cbase) * 49 + lane;
  float*       myt     = tile[wave];

  if (li != 3) {
    // ======== vectorized path (W % 4 == 0): width-16 DMA, never crosses a row ========
    int cnt4 = regH * row4;
    if (cnt4 > TILE_F / 4) cnt4 = TILE_F / 4;   // safety (analysis: <=~443)
    // per-lane staging offsets, channel-invariant (plane-relative float index)
    int soff[MAXI];
#pragma unroll
    for (int i = 0; i < MAXI; ++i) {
      const int u = lane + (i << 6);
      if (u < cnt4) {
        const int r = u / row4;
        const int c = u - r * row4;
        soff[i] = r * W + x_lo4 + (c << 2);
      } else soff[i] = -1;
    }

    for (int cc = 0; cc < 16; ++cc) {
      const float* plane = plane0 + (size_t)cc * planeHW;
      // ensure previous channel's LDS reads have completed before DMA overwrites
      asm volatile("s_waitcnt lgkmcnt(0)" ::: "memory");
#pragma unroll
      for (int i = 0; i < MAXI; ++i)
        if (soff[i] >= 0) dma16(plane + soff[i], myt + (i << 8));
      asm volatile("s_waitcnt vmcnt(0)" ::: "memory");

      if (lane < 49) {
        float acc = 0.0f;
#pragma unroll
        for (int sy = 0; sy < 2; ++sy) {
#pragma unroll
          for (int sx = 0; sx < 2; ++sx) {
            const float w00 = myt[rT[sy] + Cc0[sx]];
            const float w01 = myt[rT[sy] + Cc1[sx]];
            const float w10 = myt[rB[sy] + Cc0[sx]];
            const float w11 = myt[rB[sy] + Cc1[sx]];
            const float bil = HY[sy] * (HX[sx] * w00 + LX[sx] * w01)
                            + LY[sy] * (HX[sx] * w10 + LX[sx] * w11);
            acc += (VY[sy] * VX[sx]) * bil;
          }
        }
        outp[cc * 49] = acc * 0.25f;
      }
    }
  } else {
    // ======== level-3 path (W=38): width-4 DMA of exact elements, always in-bounds ========
    int cntS = regH * regW4;
    if (cntS > TILE_F) cntS = TILE_F;

    for (int cc = 0; cc < 16; ++cc) {
      const float* plane = plane0 + (size_t)cc * planeHW;
      asm volatile("s_waitcnt lgkmcnt(0)" ::: "memory");
      for (int k = 0; (k << 6) < cntS; ++k) {
        const int u = (k << 6) + lane;
        if (u < cntS) {
          const int r   = u / regW4;
          const int c   = u - r * regW4;
          const int col = x_lo4 + c;
          if (col <= Wm1)                     // junk slots (col>Wm1) are never read
            dma4(plane + r * W + col, myt + (k << 6));
        }
      }
      asm volatile("s_waitcnt vmcnt(0)" ::: "memory");

      if (lane < 49) {
        float acc = 0.0f;
#pragma unroll
        for (int sy = 0; sy < 2; ++sy) {
#pragma unroll
          for (int sx = 0; sx < 2; ++sx) {
            const float w00 = myt[rT[sy] + Cc0[sx]];
            const float w01 = myt[rT[sy] + Cc1[sx]];
            const float w10 = myt[rB[sy] + Cc0[sx]];
            const float w11 = myt[rB[sy] + Cc1[sx]];
            const float bil = HY[sy] * (HX[sx] * w00 + LX[sx] * w01)
                            + LY[sy] * (HX[sx] * w10 + LX[sx] * w11);
            acc += (VY[sy] * VX[sx]) * bil;
          }
        }
        outp[cc * 49] = acc * 0.25f;
      }
    }
  }
}

extern "C" void kernel_launch(void* const* d_in, const int* in_sizes, int n_in,
                              void* d_out, int out_size, void* d_ws, size_t ws_size,
                              hipStream_t stream) {
  const float* f0    = (const float*)d_in[0];
  const float* f1    = (const float*)d_in[1];
  const float* f2    = (const float*)d_in[2];
  const float* f3    = (const float*)d_in[3];
  const float* boxes = (const float*)d_in[4];
  const int*   bidx  = (const int*)d_in[5];
  const int N = in_sizes[5];                 // 1024 boxes
  dim3 grid(8, N);                           // 8 groups x (2 waves x 16 ch) = 256 channels
  pooler_kernel<<<grid, 128, 0, stream>>>(f0, f1, f2, f3, boxes, bidx,
                                          (float*)d_out, N);
}